// Round 7
// baseline (351.167 us; speedup 1.0000x reference)
//
#include <hip/hip_runtime.h>

typedef _Float16 f16;
typedef f16 f16x8 __attribute__((ext_vector_type(8)));
typedef f16 f16x4 __attribute__((ext_vector_type(4)));
typedef short s16x8 __attribute__((ext_vector_type(8)));
typedef short s16x4 __attribute__((ext_vector_type(4)));
typedef float f32x4 __attribute__((ext_vector_type(4)));

#define MFMA16(a,b,c)  __builtin_amdgcn_mfma_f32_16x16x32_f16(a,b,c,0,0,0)
#define MFMAB16(a,b,c) __builtin_amdgcn_mfma_f32_16x16x32_bf16(a,b,c,0,0,0)

static constexpr int Bn = 8, Qn = 2048, Kn = 2048, Hn = 512;
static constexpr int Mn = Bn * Qn;           // 16384 flat rows

typedef __attribute__((address_space(1))) const unsigned int as1_uint;
typedef __attribute__((address_space(3))) unsigned int as3_uint;

__device__ __forceinline__ void gl_lds16(const void* g, void* l) {
    __builtin_amdgcn_global_load_lds((as1_uint*)g, (as3_uint*)l, 16, 0, 0);
}

__device__ __forceinline__ short bf16r(float x) {
    unsigned u = __builtin_bit_cast(unsigned, x);
    u += 0x7fffu + ((u >> 16) & 1u);
    return (short)(u >> 16);
}

// swizzle granule: 2-way (free) bank aliasing for ds_read_b128 column reads
__device__ __forceinline__ int swz(int row) { return (row >> 1) & 3; }

// ---------------------------------------------------------------------------
// compact_mask: per batch, order-preserving list of unmasked key indices.
// ---------------------------------------------------------------------------
__global__ __launch_bounds__(256) void compact_mask(
    const int* __restrict__ mask, int* __restrict__ cidx, int* __restrict__ cnt)
{
    __shared__ int sums[256];
    int b = blockIdx.x, t = threadIdx.x;
    int base = b * Kn + t * 8;
    int mv[8]; int s = 0;
    #pragma unroll
    for (int i = 0; i < 8; ++i) { mv[i] = (mask[base + i] == 0); s += mv[i]; }
    sums[t] = s;
    __syncthreads();
    for (int off = 1; off < 256; off <<= 1) {
        int v = (t >= off) ? sums[t - off] : 0;
        __syncthreads();
        sums[t] += v;
        __syncthreads();
    }
    int pos = (t > 0 ? sums[t - 1] : 0);
    #pragma unroll
    for (int i = 0; i < 8; ++i)
        if (mv[i]) cidx[b * Kn + pos++] = t * 8 + i;
    if (t == 255) {
        int total = sums[255];
        if (total == 0) { cidx[b * Kn] = 0; total = 1; }
        cnt[b] = total;
    }
}

// ---------------------------------------------------------------------------
// prep_split: Wk -> x512 fp16 hi/lo split; Wo -> Wot (bf16 transpose).
// ---------------------------------------------------------------------------
__global__ __launch_bounds__(256) void prep_split(
    const float* __restrict__ Wk, const float* __restrict__ Wo,
    f16* __restrict__ Wk_h, f16* __restrict__ Wk_l, short* __restrict__ Wot)
{
    int e = blockIdx.x * 256 + threadIdx.x;
    float v = Wk[e] * 512.0f;
    f16 h = (f16)v;
    Wk_h[e] = h; Wk_l[e] = (f16)((v - (float)h) * 2048.0f);
    int r = e >> 9, c = e & 511;
    Wot[c * 512 + r] = bf16r(Wo[e]);
}

// ---------------------------------------------------------------------------
// prep_vec: wvec[h] = dot(Wk[h,:], bq);  cvec[n] = bv.Wo + bo.
// ---------------------------------------------------------------------------
__global__ __launch_bounds__(512) void prep_vec(
    const float* __restrict__ Wk, const float* __restrict__ Wo,
    const float* __restrict__ bq, const float* __restrict__ bv,
    const float* __restrict__ bo,
    float* __restrict__ wvec, float* __restrict__ cvec)
{
    int t = threadIdx.x;
    float s = 0.f;
    for (int n = 0; n < 512; n += 4) {
        f32x4 a = *(const f32x4*)(Wk + (size_t)t * 512 + n);
        f32x4 q = *(const f32x4*)(bq + n);
        s += a[0]*q[0] + a[1]*q[1] + a[2]*q[2] + a[3]*q[3];
    }
    wvec[t] = s;
    float s2 = 0.f;
    for (int h = 0; h < 512; ++h) s2 += bv[h] * Wo[h * 512 + t];
    cvec[t] = s2 + bo[t];
}

// ---------------------------------------------------------------------------
// gemm_split<PREP>: fp16x2 3-product GEMM_BT, 64m x 256n tile, 4 waves
// (64-col strip each), 80KB LDS dbuf, async B staging.
//  PREP=0: qM = (A.Bt)/512, split out [m][n]  (grid Mn/64 x 2)
//  PREP=1: Mt = A.Bt (=M x512), split out TRANSPOSED [n][m] (grid 8 x 2)
// ---------------------------------------------------------------------------
template<int PREP>
__global__ __launch_bounds__(256) void gemm_split(
    const float* __restrict__ Af,
    const f16* __restrict__ Bh_g, const f16* __restrict__ Bl_g,
    f16* __restrict__ Oh, f16* __restrict__ Ol)
{
    __shared__ __align__(16) f16 Ah[2][2048], Al[2][2048], Bh[2][8192], Bl[2][8192];
    const int tid = threadIdx.x, lane = tid & 63, wid = tid >> 6;
    const int l15 = lane & 15, lg = lane >> 4;
    const int m0 = blockIdx.x * 64, n0 = blockIdx.y * 256;
    const int srow = lane >> 2, sg = lane & 3;
    const int ar0 = tid >> 3, ac0 = (tid & 7) * 4;

    auto stageB = [&](int buf, int ks) {
        const int k0 = ks << 5;
        #pragma unroll
        for (int h = 0; h < 4; ++h) {
            int s = wid + h * 4;
            int row = s * 16 + srow;
            int goff = k0 + ((sg ^ swz(row)) << 3);
            gl_lds16(Bh_g + (size_t)(n0 + row) * Hn + goff, &Bh[buf][s * 512]);
            gl_lds16(Bl_g + (size_t)(n0 + row) * Hn + goff, &Bl[buf][s * 512]);
        }
    };
    auto writeA = [&](int buf, const f32x4* av) {
        #pragma unroll
        for (int rr = 0; rr < 2; ++rr) {
            int row = ar0 + rr * 32;
            f16x4 oh, ol;
            #pragma unroll
            for (int j = 0; j < 4; ++j) {
                f16 hh = (f16)av[rr][j];
                oh[j] = hh;
                ol[j] = (f16)((av[rr][j] - (float)hh) * 2048.0f);
            }
            int off = row * 32 + (((ac0 >> 3) ^ swz(row)) << 3) + (ac0 & 7);
            *(f16x4*)&Ah[buf][off] = oh;
            *(f16x4*)&Al[buf][off] = ol;
        }
    };

    const float* aSrc[2];
    #pragma unroll
    for (int rr = 0; rr < 2; ++rr)
        aSrc[rr] = Af + (size_t)(m0 + ar0 + rr * 32) * Hn;

    f32x4 a0[4][4] = {}, a1[4][4] = {};
    {
        f32x4 av[2];
        #pragma unroll
        for (int rr = 0; rr < 2; ++rr) av[rr] = *(const f32x4*)(aSrc[rr] + ac0);
        stageB(0, 0);
        writeA(0, av);
    }
    __syncthreads();
    #pragma unroll 1
    for (int ks = 0; ks < 16; ++ks) {
        const int cur = ks & 1, nxt = cur ^ 1;
        f32x4 av[2];
        if (ks < 15) {
            const int k1 = (ks + 1) << 5;
            #pragma unroll
            for (int rr = 0; rr < 2; ++rr) av[rr] = *(const f32x4*)(aSrc[rr] + k1 + ac0);
            stageB(nxt, ks + 1);
        }
        f16x8 fbh[4], fbl[4];
        #pragma unroll
        for (int fj = 0; fj < 4; ++fj) {
            int row = wid * 64 + fj * 16 + l15;
            int off = row * 32 + ((lg ^ swz(row)) << 3);
            fbh[fj] = *(f16x8*)&Bh[cur][off];
            fbl[fj] = *(f16x8*)&Bl[cur][off];
        }
        #pragma unroll
        for (int fi = 0; fi < 4; ++fi) {
            int row = fi * 16 + l15;
            int off = row * 32 + ((lg ^ swz(row)) << 3);
            f16x8 fah = *(f16x8*)&Ah[cur][off];
            f16x8 fal = *(f16x8*)&Al[cur][off];
            #pragma unroll
            for (int fj = 0; fj < 4; ++fj) {
                a0[fi][fj] = MFMA16(fah, fbh[fj], a0[fi][fj]);
                a1[fi][fj] = MFMA16(fah, fbl[fj], a1[fi][fj]);
                a1[fi][fj] = MFMA16(fal, fbh[fj], a1[fi][fj]);
            }
        }
        if (ks < 15) writeA(nxt, av);
        __syncthreads();
    }
    #pragma unroll
    for (int fi = 0; fi < 4; ++fi)
    #pragma unroll
    for (int fj = 0; fj < 4; ++fj)
    #pragma unroll
    for (int j = 0; j < 4; ++j) {
        int m = m0 + fi * 16 + lg * 4 + j;
        int n = n0 + wid * 64 + fj * 16 + l15;
        float v = a0[fi][fj][j] + a1[fi][fj][j] * (1.0f / 2048.0f);
        if (PREP == 0) v *= (1.0f / 512.0f);
        f16 h = (f16)v;
        f16 lo = (f16)((v - (float)h) * 2048.0f);
        size_t o = PREP ? ((size_t)n * Hn + m) : ((size_t)m * Hn + n);
        Oh[o] = h; Ol[o] = lo;
    }
}

// ---------------------------------------------------------------------------
// gemm_bfk<MODE>: bf16 GEMM_BT, 64m x 128n tile, A f32->bf16 on the fly.
//  MODE=0: NtB prep — A=Wv direct rows, out bf16 TRANSPOSED [n][m], no bias.
//  MODE=1: res — A rows gathered from value via idxArr, out f32 + cvec.
// ---------------------------------------------------------------------------
template<int MODE>
__global__ __launch_bounds__(256) void gemm_bfk(
    const float* __restrict__ Af, const short* __restrict__ Bt,
    const float* __restrict__ cvec, const int* __restrict__ idxArr,
    void* __restrict__ Out)
{
    __shared__ __align__(16) short As[2][2048], Bs[2][4096];
    const int tid = threadIdx.x, lane = tid & 63, wid = tid >> 6;
    const int l15 = lane & 15, lg = lane >> 4;
    const int m0 = blockIdx.x * 64, n0 = blockIdx.y * 128;
    const int srow = lane >> 2, sg = lane & 3;
    const int ar0 = tid >> 3, ac0 = (tid & 7) * 4;

    const float* aSrc[2];
    #pragma unroll
    for (int rr = 0; rr < 2; ++rr) {
        int row = ar0 + rr * 32;
        size_t grow;
        if (MODE == 1) {
            int b = m0 >> 11;
            grow = (size_t)(b * Kn + idxArr[m0 + row]);
        } else {
            grow = (size_t)(m0 + row);
        }
        aSrc[rr] = Af + grow * Hn;
    }

    auto stageB = [&](int buf, int ks) {
        const int k0 = ks << 5;
        #pragma unroll
        for (int h = 0; h < 2; ++h) {
            int s = wid + h * 4;
            int row = s * 16 + srow;
            int goff = k0 + ((sg ^ swz(row)) << 3);
            gl_lds16(Bt + (size_t)(n0 + row) * Hn + goff, &Bs[buf][s * 512]);
        }
    };
    auto writeA = [&](int buf, const f32x4* av) {
        #pragma unroll
        for (int rr = 0; rr < 2; ++rr) {
            int row = ar0 + rr * 32;
            s16x4 o;
            #pragma unroll
            for (int j = 0; j < 4; ++j) o[j] = bf16r(av[rr][j]);
            int off = row * 32 + (((ac0 >> 3) ^ swz(row)) << 3) + (ac0 & 7);
            *(s16x4*)&As[buf][off] = o;
        }
    };

    f32x4 acc[4][2] = {};
    {
        f32x4 av[2];
        #pragma unroll
        for (int rr = 0; rr < 2; ++rr) av[rr] = *(const f32x4*)(aSrc[rr] + ac0);
        stageB(0, 0);
        writeA(0, av);
    }
    __syncthreads();
    #pragma unroll 1
    for (int ks = 0; ks < 16; ++ks) {
        const int cur = ks & 1, nxt = cur ^ 1;
        f32x4 av[2];
        if (ks < 15) {
            const int k1 = (ks + 1) << 5;
            #pragma unroll
            for (int rr = 0; rr < 2; ++rr) av[rr] = *(const f32x4*)(aSrc[rr] + k1 + ac0);
            stageB(nxt, ks + 1);
        }
        s16x8 fb[2];
        #pragma unroll
        for (int fj = 0; fj < 2; ++fj) {
            int row = wid * 32 + fj * 16 + l15;
            fb[fj] = *(s16x8*)&Bs[cur][row * 32 + ((lg ^ swz(row)) << 3)];
        }
        #pragma unroll
        for (int fi = 0; fi < 4; ++fi) {
            int row = fi * 16 + l15;
            s16x8 fa = *(s16x8*)&As[cur][row * 32 + ((lg ^ swz(row)) << 3)];
            #pragma unroll
            for (int fj = 0; fj < 2; ++fj)
                acc[fi][fj] = MFMAB16(fa, fb[fj], acc[fi][fj]);
        }
        if (ks < 15) writeA(nxt, av);
        __syncthreads();
    }
    #pragma unroll
    for (int fi = 0; fi < 4; ++fi)
    #pragma unroll
    for (int fj = 0; fj < 2; ++fj)
    #pragma unroll
    for (int j = 0; j < 4; ++j) {
        int m = m0 + fi * 16 + lg * 4 + j;
        int n = n0 + wid * 32 + fj * 16 + l15;
        if (MODE == 0) {
            ((short*)Out)[(size_t)n * Hn + m] = bf16r(acc[fi][fj][j]);
        } else {
            ((float*)Out)[(size_t)m * Hn + n] = acc[fi][fj][j] + cvec[n];
        }
    }
}

// ---------------------------------------------------------------------------
// kconv: gathered raw-k rows -> fp16 hi/lo split (compacted layout) + beta.
// ---------------------------------------------------------------------------
__global__ __launch_bounds__(256) void kconv(
    const float* __restrict__ key_, const int* __restrict__ cidx,
    const int* __restrict__ cnt, const float* __restrict__ wvec,
    f16* __restrict__ Kc_h, f16* __restrict__ Kc_l, float* __restrict__ beta)
{
    int wid = threadIdx.x >> 6, lane = threadIdx.x & 63;
    int b = blockIdx.y, j = blockIdx.x * 4 + wid;
    int cn = cnt[b];
    if (j >= cn) return;
    const float* src = key_ + (size_t)(b * Kn + cidx[b * Kn + j]) * Hn;
    size_t dst = (size_t)(b * Kn + j) * Hn;
    float s = 0.f;
    #pragma unroll
    for (int i = 0; i < 2; ++i) {
        int c0 = lane * 8 + i * 4;
        f32x4 v = *(const f32x4*)(src + c0);
        f32x4 w = *(const f32x4*)(wvec + c0);
        f16x4 oh, ol;
        #pragma unroll
        for (int e = 0; e < 4; ++e) {
            f16 h = (f16)v[e];
            oh[e] = h;
            ol[e] = (f16)((v[e] - (float)h) * 2048.0f);
            s += v[e] * w[e];
        }
        *(f16x4*)(Kc_h + dst + c0) = oh;
        *(f16x4*)(Kc_l + dst + c0) = ol;
    }
    #pragma unroll
    for (int sm = 1; sm < 64; sm <<= 1) s += __shfl_xor(s, sm, 64);
    if (lane == 0) beta[b * Kn + j] = s;
}

// ---------------------------------------------------------------------------
// energy_argmax: 64q x 256k tile, 4 waves (64-col strip each), 80KB LDS.
// bwv/bwi reuse the A-buffers after the K-loop.
// ---------------------------------------------------------------------------
__global__ __launch_bounds__(256) void energy_argmax(
    const f16* __restrict__ Qh, const f16* __restrict__ Ql,
    const f16* __restrict__ Kh, const f16* __restrict__ Kl,
    const float* __restrict__ beta, const int* __restrict__ cnt,
    float* __restrict__ pval, int* __restrict__ pidx)
{
    __shared__ __align__(16) f16 Ah[2][2048], Al[2][2048], Bh[2][8192], Bl[2][8192];
    const int tid = threadIdx.x, lane = tid & 63, wid = tid >> 6;
    const int l15 = lane & 15, lg = lane >> 4;
    const int qt = blockIdx.x, kc = blockIdx.y, b = blockIdx.z;
    const int cn = cnt[b];
    const int kbase = kc << 8;
    if (kbase >= cn) return;
    const int m0 = b * Qn + qt * 64;
    const int kr0 = b * Kn + kbase;
    const float NEGINF = -__builtin_inff();
    const int srow = lane >> 2, sg = lane & 3;

    auto stage = [&](int buf, int ks) {
        const int k0 = ks << 5;
        {
            int row = wid * 16 + srow;
            int goff = k0 + ((sg ^ swz(row)) << 3);
            size_t ga = (size_t)(m0 + row) * Hn + goff;
            gl_lds16(Qh + ga, &Ah[buf][wid * 512]);
            gl_lds16(Ql + ga, &Al[buf][wid * 512]);
        }
        #pragma unroll
        for (int h = 0; h < 4; ++h) {
            int s = wid + h * 4;
            int row = s * 16 + srow;
            int goff = k0 + ((sg ^ swz(row)) << 3);
            size_t gb = (size_t)(kr0 + row) * Hn + goff;
            gl_lds16(Kh + gb, &Bh[buf][s * 512]);
            gl_lds16(Kl + gb, &Bl[buf][s * 512]);
        }
    };

    f32x4 a0[4][4] = {}, a1[4][4] = {};
    stage(0, 0);
    __syncthreads();
    #pragma unroll 1
    for (int ks = 0; ks < 16; ++ks) {
        const int cur = ks & 1;
        if (ks < 15) stage(cur ^ 1, ks + 1);
        f16x8 fbh[4], fbl[4];
        #pragma unroll
        for (int fj = 0; fj < 4; ++fj) {
            int row = wid * 64 + fj * 16 + l15;
            int off = row * 32 + ((lg ^ swz(row)) << 3);
            fbh[fj] = *(f16x8*)&Bh[cur][off];
            fbl[fj] = *(f16x8*)&Bl[cur][off];
        }
        #pragma unroll
        for (int fi = 0; fi < 4; ++fi) {
            int row = fi * 16 + l15;
            int off = row * 32 + ((lg ^ swz(row)) << 3);
            f16x8 fah = *(f16x8*)&Ah[cur][off];
            f16x8 fal = *(f16x8*)&Al[cur][off];
            #pragma unroll
            for (int fj = 0; fj < 4; ++fj) {
                a0[fi][fj] = MFMA16(fah, fbh[fj], a0[fi][fj]);
                a1[fi][fj] = MFMA16(fah, fbl[fj], a1[fi][fj]);
                a1[fi][fj] = MFMA16(fal, fbh[fj], a1[fi][fj]);
            }
        }
        __syncthreads();
    }
    // reuse A-buffers for the per-wave reduction scratch (K-loop done)
    float (*bwv)[64] = (float(*)[64])&Ah[0][0];   // 4x64 f32 = 1KB
    int   (*bwi)[64] = (int(*)[64])&Al[0][0];
    float bet[4];
    #pragma unroll
    for (int fj = 0; fj < 4; ++fj) {
        int lc = wid * 64 + fj * 16 + l15;
        bet[fj] = beta[b * Kn + kbase + lc];
    }
    #pragma unroll
    for (int fi = 0; fi < 4; ++fi) {
        #pragma unroll
        for (int j = 0; j < 4; ++j) {
            float bv = NEGINF; int bc = 0x7fffffff;
            #pragma unroll
            for (int fj = 0; fj < 4; ++fj) {
                int lc = wid * 64 + fj * 16 + l15;
                float v = a0[fi][fj][j] + a1[fi][fj][j] * (1.0f / 2048.0f) + bet[fj];
                v = (kbase + lc < cn) ? v : NEGINF;
                if (v > bv || (v == bv && lc < bc)) { bv = v; bc = lc; }
            }
            #pragma unroll
            for (int sm = 1; sm < 16; sm <<= 1) {
                float ov = __shfl_xor(bv, sm, 64);
                int   oc = __shfl_xor(bc, sm, 64);
                if (ov > bv || (ov == bv && oc < bc)) { bv = ov; bc = oc; }
            }
            if (l15 == 0) {
                int row = fi * 16 + lg * 4 + j;
                bwv[wid][row] = bv; bwi[wid][row] = bc;
            }
        }
    }
    __syncthreads();
    if (tid < 64) {
        float bv = bwv[0][tid]; int bc = bwi[0][tid];
        #pragma unroll
        for (int s = 1; s < 4; ++s) {
            float v = bwv[s][tid]; int i = bwi[s][tid];
            if (v > bv || (v == bv && i < bc)) { bv = v; bc = i; }
        }
        int m = m0 + tid;
        pval[m * 16 + kc] = bv;
        pidx[m * 16 + kc] = kbase + bc;
    }
}

// ---------------------------------------------------------------------------
// merge: chunk partials -> original-index argmax per row.
// ---------------------------------------------------------------------------
__global__ __launch_bounds__(256) void merge(
    const float* __restrict__ pval, const int* __restrict__ pidx,
    const int* __restrict__ cnt, const int* __restrict__ cidx,
    int* __restrict__ idxArr)
{
    int m = blockIdx.x * 256 + threadIdx.x;
    int b = m >> 11;
    int nc = (cnt[b] + 255) >> 8;
    float bv = -__builtin_inff(); int bi = 0x7fffffff;
    for (int c = 0; c < nc; ++c) {
        float v = pval[m * 16 + c]; int i = pidx[m * 16 + c];
        if (v > bv || (v == bv && i < bi)) { bv = v; bi = i; }
    }
    idxArr[m] = cidx[b * Kn + bi];
}

// ---------------------------------------------------------------------------
// score_fill: one-hot rows, writes the ENTIRE score region (erases scratch).
// ---------------------------------------------------------------------------
__global__ __launch_bounds__(256) void score_fill(
    const int* __restrict__ idxArr, float* __restrict__ score)
{
    int m = blockIdx.x;
    int c = idxArr[m];
    float* row = score + (size_t)m * Kn;
    int t = threadIdx.x;
    #pragma unroll
    for (int i = 0; i < 2; ++i) {
        int v = t + i * 256;
        f32x4 val = {0.f, 0.f, 0.f, 0.f};
        if ((c >> 2) == v) val[c & 3] = 1.0f;
        *(f32x4*)(row + v * 4) = val;
    }
}

// ---------------------------------------------------------------------------
extern "C" void kernel_launch(void* const* d_in, const int* in_sizes, int n_in,
                              void* d_out, int out_size, void* d_ws, size_t ws_size,
                              hipStream_t stream)
{
    const float* query = (const float*)d_in[0];
    const float* key_  = (const float*)d_in[1];
    const float* value = (const float*)d_in[2];
    const int*   mask  = (const int*)d_in[3];
    const float* Wq = (const float*)d_in[4];
    const float* bq = (const float*)d_in[5];
    const float* Wk = (const float*)d_in[6];
    const float* bv = (const float*)d_in[9];
    const float* Wv = (const float*)d_in[8];
    const float* Wo = (const float*)d_in[10];
    const float* bo = (const float*)d_in[11];

    float* res = (float*)d_out;                       // (B,Q,H) f32
    float* scoreBase = res + (size_t)Mn * Hn;         // (B,Q,K) f32, 134 MB
    char* sc = (char*)scoreBase;                      // scratch inside score region
    constexpr size_t MB = 1u << 20;
    f16*   qM_h = (f16*)(sc + 0 * MB);
    f16*   qM_l = (f16*)(sc + 16 * MB);
    f16*   Kc_h = (f16*)(sc + 32 * MB);
    f16*   Kc_l = (f16*)(sc + 48 * MB);
    f16*   Mt_h = (f16*)(sc + 64 * MB);
    f16*   Mt_l = (f16*)(sc + 64 * MB + 524288);
    f16*   Wk_h = (f16*)(sc + 65 * MB);
    f16*   Wk_l = (f16*)(sc + 65 * MB + 524288);
    short* Wot  = (short*)(sc + 66 * MB);
    short* NtB  = (short*)(sc + 66 * MB + 524288);
    float* wvec = (float*)(sc + 67 * MB);
    float* cvec = (float*)(sc + 67 * MB + 4096);
    float* beta = (float*)(sc + 67 * MB + 8192);                 // 64 KB
    float* pval = (float*)(sc + 67 * MB + 8192 + 65536);         // 1 MB
    int*   pidx = (int*)(sc + 68 * MB + 8192 + 65536);           // 1 MB
    int*   cidx = (int*)(sc + 69 * MB + 8192 + 65536);           // 64 KB

    int*   idxArr = (int*)d_ws;                       // Mn ints
    int*   cnt    = (int*)d_ws + Mn;                  // 8 ints

    compact_mask<<<Bn, 256, 0, stream>>>(mask, cidx, cnt);
    prep_split<<<1024, 256, 0, stream>>>(Wk, Wo, Wk_h, Wk_l, Wot);
    prep_vec<<<1, 512, 0, stream>>>(Wk, Wo, bq, bv, bo, wvec, cvec);

    // Mt = (Wq . Wk^T) x512, split, transposed  (tiny)
    gemm_split<1><<<dim3(8, 2), 256, 0, stream>>>(Wq, Wk_h, Wk_l, Mt_h, Mt_l);
    // NtB = (Wv . Wo)^T bf16  (tiny)
    gemm_bfk<0><<<dim3(8, 4), 256, 0, stream>>>(Wv, Wot, nullptr, nullptr, NtB);
    // qM = query . M  (the only big projection GEMM left)
    gemm_split<0><<<dim3(Mn / 64, 2), 256, 0, stream>>>(query, Mt_h, Mt_l, qM_h, qM_l);
    // raw-k split + beta
    kconv<<<dim3(512, Bn), 256, 0, stream>>>(key_, cidx, cnt, wvec, Kc_h, Kc_l, beta);

    energy_argmax<<<dim3(Qn / 64, 8, Bn), 256, 0, stream>>>(
        qM_h, qM_l, Kc_h, Kc_l, beta, cnt, pval, pidx);

    merge<<<Mn / 256, 256, 0, stream>>>(pval, pidx, cnt, cidx, idxArr);

    // res = value[argmax] . N + c   (gathered A, one GEMM)
    gemm_bfk<1><<<dim3(Mn / 64, 4), 256, 0, stream>>>(value, NtB, cvec, idxArr, res);

    score_fill<<<Mn, 256, 0, stream>>>(idxArr, scoreBase);
}

// Round 8
// 288.321 us; speedup vs baseline: 1.2180x; 1.2180x over previous
//
#include <hip/hip_runtime.h>

typedef _Float16 f16;
typedef f16 f16x8 __attribute__((ext_vector_type(8)));
typedef f16 f16x4 __attribute__((ext_vector_type(4)));
typedef short s16x8 __attribute__((ext_vector_type(8)));
typedef short s16x4 __attribute__((ext_vector_type(4)));
typedef float f32x4 __attribute__((ext_vector_type(4)));

#define MFMA16(a,b,c)  __builtin_amdgcn_mfma_f32_16x16x32_f16(a,b,c,0,0,0)
#define MFMAB16(a,b,c) __builtin_amdgcn_mfma_f32_16x16x32_bf16(a,b,c,0,0,0)

static constexpr int Bn = 8, Qn = 2048, Kn = 2048, Hn = 512;
static constexpr int Mn = Bn * Qn;           // 16384 flat rows

typedef __attribute__((address_space(1))) const unsigned int as1_uint;
typedef __attribute__((address_space(3))) unsigned int as3_uint;

__device__ __forceinline__ void gl_lds16(const void* g, void* l) {
    __builtin_amdgcn_global_load_lds((as1_uint*)g, (as3_uint*)l, 16, 0, 0);
}

__device__ __forceinline__ short bf16r(float x) {
    unsigned u = __builtin_bit_cast(unsigned, x);
    u += 0x7fffu + ((u >> 16) & 1u);
    return (short)(u >> 16);
}

// swizzle granule: 2-way (free) bank aliasing for ds_read_b128 column reads
__device__ __forceinline__ int swz(int row) { return (row >> 1) & 3; }

// ---------------------------------------------------------------------------
// compact_mask: per batch, order-preserving list of unmasked key indices.
// ---------------------------------------------------------------------------
__global__ __launch_bounds__(256) void compact_mask(
    const int* __restrict__ mask, int* __restrict__ cidx, int* __restrict__ cnt)
{
    __shared__ int sums[256];
    int b = blockIdx.x, t = threadIdx.x;
    int base = b * Kn + t * 8;
    int mv[8]; int s = 0;
    #pragma unroll
    for (int i = 0; i < 8; ++i) { mv[i] = (mask[base + i] == 0); s += mv[i]; }
    sums[t] = s;
    __syncthreads();
    for (int off = 1; off < 256; off <<= 1) {
        int v = (t >= off) ? sums[t - off] : 0;
        __syncthreads();
        sums[t] += v;
        __syncthreads();
    }
    int pos = (t > 0 ? sums[t - 1] : 0);
    #pragma unroll
    for (int i = 0; i < 8; ++i)
        if (mv[i]) cidx[b * Kn + pos++] = t * 8 + i;
    if (t == 255) {
        int total = sums[255];
        if (total == 0) { cidx[b * Kn] = 0; total = 1; }
        cnt[b] = total;
    }
}

// ---------------------------------------------------------------------------
// prep_split: Wk -> x512 fp16 hi/lo split; Wo -> Wot (bf16 transpose).
// ---------------------------------------------------------------------------
__global__ __launch_bounds__(256) void prep_split(
    const float* __restrict__ Wk, const float* __restrict__ Wo,
    f16* __restrict__ Wk_h, f16* __restrict__ Wk_l, short* __restrict__ Wot)
{
    int e = blockIdx.x * 256 + threadIdx.x;
    float v = Wk[e] * 512.0f;
    f16 h = (f16)v;
    Wk_h[e] = h; Wk_l[e] = (f16)((v - (float)h) * 2048.0f);
    int r = e >> 9, c = e & 511;
    Wot[c * 512 + r] = bf16r(Wo[e]);
}

// ---------------------------------------------------------------------------
// prep_vec: wvec[h] = dot(Wk[h,:], bq);  cvec[n] = bv.Wo + bo.
// ---------------------------------------------------------------------------
__global__ __launch_bounds__(512) void prep_vec(
    const float* __restrict__ Wk, const float* __restrict__ Wo,
    const float* __restrict__ bq, const float* __restrict__ bv,
    const float* __restrict__ bo,
    float* __restrict__ wvec, float* __restrict__ cvec)
{
    int t = threadIdx.x;
    float s = 0.f;
    for (int n = 0; n < 512; n += 4) {
        f32x4 a = *(const f32x4*)(Wk + (size_t)t * 512 + n);
        f32x4 q = *(const f32x4*)(bq + n);
        s += a[0]*q[0] + a[1]*q[1] + a[2]*q[2] + a[3]*q[3];
    }
    wvec[t] = s;
    float s2 = 0.f;
    for (int h = 0; h < 512; ++h) s2 += bv[h] * Wo[h * 512 + t];
    cvec[t] = s2 + bo[t];
}

// ---------------------------------------------------------------------------
// gemm_split<PREP>: fp16x2 3-product GEMM_BT, 64m x 128n tile, 4 waves
// (32-col strip each), 48KB LDS dbuf, async B staging.
//  PREP=0: qM = (A.Bt)/512, split out [m][n]  (grid Mn/64 x 4)
//  PREP=1: Mt = A.Bt (=M x512), split out TRANSPOSED [n][m] (grid 8 x 4)
// ---------------------------------------------------------------------------
template<int PREP>
__global__ __launch_bounds__(256) void gemm_split(
    const float* __restrict__ Af,
    const f16* __restrict__ Bh_g, const f16* __restrict__ Bl_g,
    f16* __restrict__ Oh, f16* __restrict__ Ol)
{
    __shared__ __align__(16) f16 Ah[2][2048], Al[2][2048], Bh[2][4096], Bl[2][4096];
    const int tid = threadIdx.x, lane = tid & 63, wid = tid >> 6;
    const int l15 = lane & 15, lg = lane >> 4;
    const int m0 = blockIdx.x * 64, n0 = blockIdx.y * 128;
    const int srow = lane >> 2, sg = lane & 3;
    const int ar0 = tid >> 3, ac0 = (tid & 7) * 4;

    auto stageB = [&](int buf, int ks) {
        const int k0 = ks << 5;
        #pragma unroll
        for (int h = 0; h < 2; ++h) {
            int s = wid + h * 4;
            int row = s * 16 + srow;
            int goff = k0 + ((sg ^ swz(row)) << 3);
            gl_lds16(Bh_g + (size_t)(n0 + row) * Hn + goff, &Bh[buf][s * 512]);
            gl_lds16(Bl_g + (size_t)(n0 + row) * Hn + goff, &Bl[buf][s * 512]);
        }
    };
    auto writeA = [&](int buf, const f32x4* av) {
        #pragma unroll
        for (int rr = 0; rr < 2; ++rr) {
            int row = ar0 + rr * 32;
            f16x4 oh, ol;
            #pragma unroll
            for (int j = 0; j < 4; ++j) {
                f16 hh = (f16)av[rr][j];
                oh[j] = hh;
                ol[j] = (f16)((av[rr][j] - (float)hh) * 2048.0f);
            }
            int off = row * 32 + (((ac0 >> 3) ^ swz(row)) << 3) + (ac0 & 7);
            *(f16x4*)&Ah[buf][off] = oh;
            *(f16x4*)&Al[buf][off] = ol;
        }
    };

    const float* aSrc[2];
    #pragma unroll
    for (int rr = 0; rr < 2; ++rr)
        aSrc[rr] = Af + (size_t)(m0 + ar0 + rr * 32) * Hn;

    f32x4 a0[4][2] = {}, a1[4][2] = {};
    {
        f32x4 av[2];
        #pragma unroll
        for (int rr = 0; rr < 2; ++rr) av[rr] = *(const f32x4*)(aSrc[rr] + ac0);
        stageB(0, 0);
        writeA(0, av);
    }
    __syncthreads();
    #pragma unroll 1
    for (int ks = 0; ks < 16; ++ks) {
        const int cur = ks & 1, nxt = cur ^ 1;
        f32x4 av[2];
        if (ks < 15) {
            const int k1 = (ks + 1) << 5;
            #pragma unroll
            for (int rr = 0; rr < 2; ++rr) av[rr] = *(const f32x4*)(aSrc[rr] + k1 + ac0);
            stageB(nxt, ks + 1);
        }
        f16x8 fbh[2], fbl[2];
        #pragma unroll
        for (int fj = 0; fj < 2; ++fj) {
            int row = wid * 32 + fj * 16 + l15;
            int off = row * 32 + ((lg ^ swz(row)) << 3);
            fbh[fj] = *(f16x8*)&Bh[cur][off];
            fbl[fj] = *(f16x8*)&Bl[cur][off];
        }
        #pragma unroll
        for (int fi = 0; fi < 4; ++fi) {
            int row = fi * 16 + l15;
            int off = row * 32 + ((lg ^ swz(row)) << 3);
            f16x8 fah = *(f16x8*)&Ah[cur][off];
            f16x8 fal = *(f16x8*)&Al[cur][off];
            #pragma unroll
            for (int fj = 0; fj < 2; ++fj) {
                a0[fi][fj] = MFMA16(fah, fbh[fj], a0[fi][fj]);
                a1[fi][fj] = MFMA16(fah, fbl[fj], a1[fi][fj]);
                a1[fi][fj] = MFMA16(fal, fbh[fj], a1[fi][fj]);
            }
        }
        if (ks < 15) writeA(nxt, av);
        __syncthreads();
    }
    #pragma unroll
    for (int fi = 0; fi < 4; ++fi)
    #pragma unroll
    for (int fj = 0; fj < 2; ++fj)
    #pragma unroll
    for (int j = 0; j < 4; ++j) {
        int m = m0 + fi * 16 + lg * 4 + j;
        int n = n0 + wid * 32 + fj * 16 + l15;
        float v = a0[fi][fj][j] + a1[fi][fj][j] * (1.0f / 2048.0f);
        if (PREP == 0) v *= (1.0f / 512.0f);
        f16 h = (f16)v;
        f16 lo = (f16)((v - (float)h) * 2048.0f);
        size_t o = PREP ? ((size_t)n * Hn + m) : ((size_t)m * Hn + n);
        Oh[o] = h; Ol[o] = lo;
    }
}

// ---------------------------------------------------------------------------
// gemm_bfk<MODE>: bf16 GEMM_BT, 64m x 128n tile, A f32->bf16 on the fly.
//  MODE=0: NtB prep — A=Wv direct rows, out bf16 TRANSPOSED [n][m], no bias.
//  MODE=1: res — A rows gathered from value via idxArr, out f32 + cvec.
// ---------------------------------------------------------------------------
template<int MODE>
__global__ __launch_bounds__(256) void gemm_bfk(
    const float* __restrict__ Af, const short* __restrict__ Bt,
    const float* __restrict__ cvec, const int* __restrict__ idxArr,
    void* __restrict__ Out)
{
    __shared__ __align__(16) short As[2][2048], Bs[2][4096];
    const int tid = threadIdx.x, lane = tid & 63, wid = tid >> 6;
    const int l15 = lane & 15, lg = lane >> 4;
    const int m0 = blockIdx.x * 64, n0 = blockIdx.y * 128;
    const int srow = lane >> 2, sg = lane & 3;
    const int ar0 = tid >> 3, ac0 = (tid & 7) * 4;

    const float* aSrc[2];
    #pragma unroll
    for (int rr = 0; rr < 2; ++rr) {
        int row = ar0 + rr * 32;
        size_t grow;
        if (MODE == 1) {
            int b = m0 >> 11;
            grow = (size_t)(b * Kn + idxArr[m0 + row]);
        } else {
            grow = (size_t)(m0 + row);
        }
        aSrc[rr] = Af + grow * Hn;
    }

    auto stageB = [&](int buf, int ks) {
        const int k0 = ks << 5;
        #pragma unroll
        for (int h = 0; h < 2; ++h) {
            int s = wid + h * 4;
            int row = s * 16 + srow;
            int goff = k0 + ((sg ^ swz(row)) << 3);
            gl_lds16(Bt + (size_t)(n0 + row) * Hn + goff, &Bs[buf][s * 512]);
        }
    };
    auto writeA = [&](int buf, const f32x4* av) {
        #pragma unroll
        for (int rr = 0; rr < 2; ++rr) {
            int row = ar0 + rr * 32;
            s16x4 o;
            #pragma unroll
            for (int j = 0; j < 4; ++j) o[j] = bf16r(av[rr][j]);
            int off = row * 32 + (((ac0 >> 3) ^ swz(row)) << 3) + (ac0 & 7);
            *(s16x4*)&As[buf][off] = o;
        }
    };

    f32x4 acc[4][2] = {};
    {
        f32x4 av[2];
        #pragma unroll
        for (int rr = 0; rr < 2; ++rr) av[rr] = *(const f32x4*)(aSrc[rr] + ac0);
        stageB(0, 0);
        writeA(0, av);
    }
    __syncthreads();
    #pragma unroll 1
    for (int ks = 0; ks < 16; ++ks) {
        const int cur = ks & 1, nxt = cur ^ 1;
        f32x4 av[2];
        if (ks < 15) {
            const int k1 = (ks + 1) << 5;
            #pragma unroll
            for (int rr = 0; rr < 2; ++rr) av[rr] = *(const f32x4*)(aSrc[rr] + k1 + ac0);
            stageB(nxt, ks + 1);
        }
        s16x8 fb[2];
        #pragma unroll
        for (int fj = 0; fj < 2; ++fj) {
            int row = wid * 32 + fj * 16 + l15;
            fb[fj] = *(s16x8*)&Bs[cur][row * 32 + ((lg ^ swz(row)) << 3)];
        }
        #pragma unroll
        for (int fi = 0; fi < 4; ++fi) {
            int row = fi * 16 + l15;
            s16x8 fa = *(s16x8*)&As[cur][row * 32 + ((lg ^ swz(row)) << 3)];
            #pragma unroll
            for (int fj = 0; fj < 2; ++fj)
                acc[fi][fj] = MFMAB16(fa, fb[fj], acc[fi][fj]);
        }
        if (ks < 15) writeA(nxt, av);
        __syncthreads();
    }
    #pragma unroll
    for (int fi = 0; fi < 4; ++fi)
    #pragma unroll
    for (int fj = 0; fj < 2; ++fj)
    #pragma unroll
    for (int j = 0; j < 4; ++j) {
        int m = m0 + fi * 16 + lg * 4 + j;
        int n = n0 + wid * 32 + fj * 16 + l15;
        if (MODE == 0) {
            ((short*)Out)[(size_t)n * Hn + m] = bf16r(acc[fi][fj][j]);
        } else {
            ((float*)Out)[(size_t)m * Hn + n] = acc[fi][fj][j] + cvec[n];
        }
    }
}

// ---------------------------------------------------------------------------
// kconv: gathered raw-k rows -> fp16 hi/lo split (compacted layout) + beta.
// ---------------------------------------------------------------------------
__global__ __launch_bounds__(256) void kconv(
    const float* __restrict__ key_, const int* __restrict__ cidx,
    const int* __restrict__ cnt, const float* __restrict__ wvec,
    f16* __restrict__ Kc_h, f16* __restrict__ Kc_l, float* __restrict__ beta)
{
    int wid = threadIdx.x >> 6, lane = threadIdx.x & 63;
    int b = blockIdx.y, j = blockIdx.x * 4 + wid;
    int cn = cnt[b];
    if (j >= cn) return;
    const float* src = key_ + (size_t)(b * Kn + cidx[b * Kn + j]) * Hn;
    size_t dst = (size_t)(b * Kn + j) * Hn;
    float s = 0.f;
    #pragma unroll
    for (int i = 0; i < 2; ++i) {
        int c0 = lane * 8 + i * 4;
        f32x4 v = *(const f32x4*)(src + c0);
        f32x4 w = *(const f32x4*)(wvec + c0);
        f16x4 oh, ol;
        #pragma unroll
        for (int e = 0; e < 4; ++e) {
            f16 h = (f16)v[e];
            oh[e] = h;
            ol[e] = (f16)((v[e] - (float)h) * 2048.0f);
            s += v[e] * w[e];
        }
        *(f16x4*)(Kc_h + dst + c0) = oh;
        *(f16x4*)(Kc_l + dst + c0) = ol;
    }
    #pragma unroll
    for (int sm = 1; sm < 64; sm <<= 1) s += __shfl_xor(s, sm, 64);
    if (lane == 0) beta[b * Kn + j] = s;
}

// ---------------------------------------------------------------------------
// energy_argmax: 64q x 128k tile, 4 waves (32-col strip each), 48KB LDS.
// A-buffers reused for the cross-wave reduction scratch after the K-loop.
// ---------------------------------------------------------------------------
__global__ __launch_bounds__(256) void energy_argmax(
    const f16* __restrict__ Qh, const f16* __restrict__ Ql,
    const f16* __restrict__ Kh, const f16* __restrict__ Kl,
    const float* __restrict__ beta, const int* __restrict__ cnt,
    float* __restrict__ pval, int* __restrict__ pidx)
{
    __shared__ __align__(16) f16 Ah[2][2048], Al[2][2048], Bh[2][4096], Bl[2][4096];
    const int tid = threadIdx.x, lane = tid & 63, wid = tid >> 6;
    const int l15 = lane & 15, lg = lane >> 4;
    const int qt = blockIdx.x, kc = blockIdx.y, b = blockIdx.z;
    const int cn = cnt[b];
    const int kbase = kc << 7;
    if (kbase >= cn) return;
    const int m0 = b * Qn + qt * 64;
    const int kr0 = b * Kn + kbase;
    const float NEGINF = -__builtin_inff();
    const int srow = lane >> 2, sg = lane & 3;

    auto stage = [&](int buf, int ks) {
        const int k0 = ks << 5;
        {
            int row = wid * 16 + srow;
            int goff = k0 + ((sg ^ swz(row)) << 3);
            size_t ga = (size_t)(m0 + row) * Hn + goff;
            gl_lds16(Qh + ga, &Ah[buf][wid * 512]);
            gl_lds16(Ql + ga, &Al[buf][wid * 512]);
        }
        #pragma unroll
        for (int h = 0; h < 2; ++h) {
            int s = wid + h * 4;
            int row = s * 16 + srow;
            int goff = k0 + ((sg ^ swz(row)) << 3);
            size_t gb = (size_t)(kr0 + row) * Hn + goff;
            gl_lds16(Kh + gb, &Bh[buf][s * 512]);
            gl_lds16(Kl + gb, &Bl[buf][s * 512]);
        }
    };

    f32x4 a0[4][2] = {}, a1[4][2] = {};
    stage(0, 0);
    __syncthreads();
    #pragma unroll 1
    for (int ks = 0; ks < 16; ++ks) {
        const int cur = ks & 1;
        if (ks < 15) stage(cur ^ 1, ks + 1);
        f16x8 fbh[2], fbl[2];
        #pragma unroll
        for (int fj = 0; fj < 2; ++fj) {
            int row = wid * 32 + fj * 16 + l15;
            int off = row * 32 + ((lg ^ swz(row)) << 3);
            fbh[fj] = *(f16x8*)&Bh[cur][off];
            fbl[fj] = *(f16x8*)&Bl[cur][off];
        }
        #pragma unroll
        for (int fi = 0; fi < 4; ++fi) {
            int row = fi * 16 + l15;
            int off = row * 32 + ((lg ^ swz(row)) << 3);
            f16x8 fah = *(f16x8*)&Ah[cur][off];
            f16x8 fal = *(f16x8*)&Al[cur][off];
            #pragma unroll
            for (int fj = 0; fj < 2; ++fj) {
                a0[fi][fj] = MFMA16(fah, fbh[fj], a0[fi][fj]);
                a1[fi][fj] = MFMA16(fah, fbl[fj], a1[fi][fj]);
                a1[fi][fj] = MFMA16(fal, fbh[fj], a1[fi][fj]);
            }
        }
        __syncthreads();
    }
    // reuse A-buffers for cross-wave reduction scratch (K-loop done)
    float (*bwv)[64] = (float(*)[64])&Ah[0][0];
    int   (*bwi)[64] = (int(*)[64])&Al[0][0];
    float bet[2];
    #pragma unroll
    for (int fj = 0; fj < 2; ++fj) {
        int lc = wid * 32 + fj * 16 + l15;
        bet[fj] = beta[b * Kn + kbase + lc];
    }
    #pragma unroll
    for (int fi = 0; fi < 4; ++fi) {
        #pragma unroll
        for (int j = 0; j < 4; ++j) {
            float bv = NEGINF; int bc = 0x7fffffff;
            #pragma unroll
            for (int fj = 0; fj < 2; ++fj) {
                int lc = wid * 32 + fj * 16 + l15;
                float v = a0[fi][fj][j] + a1[fi][fj][j] * (1.0f / 2048.0f) + bet[fj];
                v = (kbase + lc < cn) ? v : NEGINF;
                if (v > bv || (v == bv && lc < bc)) { bv = v; bc = lc; }
            }
            #pragma unroll
            for (int sm = 1; sm < 16; sm <<= 1) {
                float ov = __shfl_xor(bv, sm, 64);
                int   oc = __shfl_xor(bc, sm, 64);
                if (ov > bv || (ov == bv && oc < bc)) { bv = ov; bc = oc; }
            }
            if (l15 == 0) {
                int row = fi * 16 + lg * 4 + j;
                bwv[wid][row] = bv; bwi[wid][row] = bc;
            }
        }
    }
    __syncthreads();
    if (tid < 64) {
        float bv = bwv[0][tid]; int bc = bwi[0][tid];
        #pragma unroll
        for (int s = 1; s < 4; ++s) {
            float v = bwv[s][tid]; int i = bwi[s][tid];
            if (v > bv || (v == bv && i < bc)) { bv = v; bc = i; }
        }
        int m = m0 + tid;
        pval[m * 16 + kc] = bv;
        pidx[m * 16 + kc] = kbase + bc;
    }
}

// ---------------------------------------------------------------------------
// merge: chunk partials -> original-index argmax per row.
// ---------------------------------------------------------------------------
__global__ __launch_bounds__(256) void merge(
    const float* __restrict__ pval, const int* __restrict__ pidx,
    const int* __restrict__ cnt, const int* __restrict__ cidx,
    int* __restrict__ idxArr)
{
    int m = blockIdx.x * 256 + threadIdx.x;
    int b = m >> 11;
    int nc = (cnt[b] + 127) >> 7;
    float bv = -__builtin_inff(); int bi = 0x7fffffff;
    for (int c = 0; c < nc; ++c) {
        float v = pval[m * 16 + c]; int i = pidx[m * 16 + c];
        if (v > bv || (v == bv && i < bi)) { bv = v; bi = i; }
    }
    idxArr[m] = cidx[b * Kn + bi];
}

// ---------------------------------------------------------------------------
// score_fill: one-hot rows, writes the ENTIRE score region (erases scratch).
// ---------------------------------------------------------------------------
__global__ __launch_bounds__(256) void score_fill(
    const int* __restrict__ idxArr, float* __restrict__ score)
{
    int m = blockIdx.x;
    int c = idxArr[m];
    float* row = score + (size_t)m * Kn;
    int t = threadIdx.x;
    #pragma unroll
    for (int i = 0; i < 2; ++i) {
        int v = t + i * 256;
        f32x4 val = {0.f, 0.f, 0.f, 0.f};
        if ((c >> 2) == v) val[c & 3] = 1.0f;
        *(f32x4*)(row + v * 4) = val;
    }
}

// ---------------------------------------------------------------------------
extern "C" void kernel_launch(void* const* d_in, const int* in_sizes, int n_in,
                              void* d_out, int out_size, void* d_ws, size_t ws_size,
                              hipStream_t stream)
{
    const float* query = (const float*)d_in[0];
    const float* key_  = (const float*)d_in[1];
    const float* value = (const float*)d_in[2];
    const int*   mask  = (const int*)d_in[3];
    const float* Wq = (const float*)d_in[4];
    const float* bq = (const float*)d_in[5];
    const float* Wk = (const float*)d_in[6];
    const float* bv = (const float*)d_in[9];
    const float* Wv = (const float*)d_in[8];
    const float* Wo = (const float*)d_in[10];
    const float* bo = (const float*)d_in[11];

    float* res = (float*)d_out;                       // (B,Q,H) f32
    float* scoreBase = res + (size_t)Mn * Hn;         // (B,Q,K) f32, 134 MB
    char* sc = (char*)scoreBase;                      // scratch inside score region
    constexpr size_t MB = 1u << 20;
    f16*   qM_h = (f16*)(sc + 0 * MB);
    f16*   qM_l = (f16*)(sc + 16 * MB);
    f16*   Kc_h = (f16*)(sc + 32 * MB);
    f16*   Kc_l = (f16*)(sc + 48 * MB);
    f16*   Mt_h = (f16*)(sc + 64 * MB);
    f16*   Mt_l = (f16*)(sc + 64 * MB + 524288);
    f16*   Wk_h = (f16*)(sc + 65 * MB);
    f16*   Wk_l = (f16*)(sc + 65 * MB + 524288);
    short* Wot  = (short*)(sc + 66 * MB);
    short* NtB  = (short*)(sc + 66 * MB + 524288);
    float* wvec = (float*)(sc + 67 * MB);
    float* cvec = (float*)(sc + 67 * MB + 4096);
    float* beta = (float*)(sc + 67 * MB + 8192);                 // 64 KB
    float* pval = (float*)(sc + 67 * MB + 8192 + 65536);         // 1 MB
    int*   pidx = (int*)(sc + 68 * MB + 8192 + 65536);           // 1 MB
    int*   cidx = (int*)(sc + 69 * MB + 8192 + 65536);           // 64 KB

    int*   idxArr = (int*)d_ws;                       // Mn ints
    int*   cnt    = (int*)d_ws + Mn;                  // 8 ints

    compact_mask<<<Bn, 256, 0, stream>>>(mask, cidx, cnt);
    prep_split<<<1024, 256, 0, stream>>>(Wk, Wo, Wk_h, Wk_l, Wot);
    prep_vec<<<1, 512, 0, stream>>>(Wk, Wo, bq, bv, bo, wvec, cvec);

    // Mt = (Wq . Wk^T) x512, split, transposed  (tiny)
    gemm_split<1><<<dim3(8, 4), 256, 0, stream>>>(Wq, Wk_h, Wk_l, Mt_h, Mt_l);
    // NtB = (Wv . Wo)^T bf16  (tiny)
    gemm_bfk<0><<<dim3(8, 4), 256, 0, stream>>>(Wv, Wot, nullptr, nullptr, NtB);
    // qM = query . M  (the only big projection GEMM left)
    gemm_split<0><<<dim3(Mn / 64, 4), 256, 0, stream>>>(query, Mt_h, Mt_l, qM_h, qM_l);
    // raw-k split + beta
    kconv<<<dim3(512, Bn), 256, 0, stream>>>(key_, cidx, cnt, wvec, Kc_h, Kc_l, beta);

    energy_argmax<<<dim3(Qn / 64, 16, Bn), 256, 0, stream>>>(
        qM_h, qM_l, Kc_h, Kc_l, beta, cnt, pval, pidx);

    merge<<<Mn / 256, 256, 0, stream>>>(pval, pidx, cnt, cidx, idxArr);

    // res = value[argmax] . N + c   (gathered A, one GEMM)
    gemm_bfk<1><<<dim3(Mn / 64, 4), 256, 0, stream>>>(value, NtB, cvec, idxArr, res);

    score_fill<<<Mn, 256, 0, stream>>>(idxArr, scoreBase);
}

// Round 9
// 243.370 us; speedup vs baseline: 1.4429x; 1.1847x over previous
//
#include <hip/hip_runtime.h>

typedef _Float16 f16;
typedef f16 f16x8 __attribute__((ext_vector_type(8)));
typedef f16 f16x4 __attribute__((ext_vector_type(4)));
typedef short s16x8 __attribute__((ext_vector_type(8)));
typedef short s16x4 __attribute__((ext_vector_type(4)));
typedef float f32x4 __attribute__((ext_vector_type(4)));

#define MFMA16(a,b,c)  __builtin_amdgcn_mfma_f32_16x16x32_f16(a,b,c,0,0,0)
#define MFMAB16(a,b,c) __builtin_amdgcn_mfma_f32_16x16x32_bf16(a,b,c,0,0,0)

static constexpr int Bn = 8, Qn = 2048, Kn = 2048, Hn = 512;
static constexpr int Mn = Bn * Qn;           // 16384 flat rows

typedef __attribute__((address_space(1))) const unsigned int as1_uint;
typedef __attribute__((address_space(3))) unsigned int as3_uint;

__device__ __forceinline__ void gl_lds16(const void* g, void* l) {
    __builtin_amdgcn_global_load_lds((as1_uint*)g, (as3_uint*)l, 16, 0, 0);
}

__device__ __forceinline__ short bf16r(float x) {
    unsigned u = __builtin_bit_cast(unsigned, x);
    u += 0x7fffu + ((u >> 16) & 1u);
    return (short)(u >> 16);
}

// swizzle granule: 2-way (free) bank aliasing for ds_read_b128 column reads
__device__ __forceinline__ int swz(int row) { return (row >> 1) & 3; }

// ---------------------------------------------------------------------------
// compact_mask: per batch, order-preserving list of unmasked key indices.
// ---------------------------------------------------------------------------
__global__ __launch_bounds__(256) void compact_mask(
    const int* __restrict__ mask, int* __restrict__ cidx, int* __restrict__ cnt)
{
    __shared__ int sums[256];
    int b = blockIdx.x, t = threadIdx.x;
    int base = b * Kn + t * 8;
    int mv[8]; int s = 0;
    #pragma unroll
    for (int i = 0; i < 8; ++i) { mv[i] = (mask[base + i] == 0); s += mv[i]; }
    sums[t] = s;
    __syncthreads();
    for (int off = 1; off < 256; off <<= 1) {
        int v = (t >= off) ? sums[t - off] : 0;
        __syncthreads();
        sums[t] += v;
        __syncthreads();
    }
    int pos = (t > 0 ? sums[t - 1] : 0);
    #pragma unroll
    for (int i = 0; i < 8; ++i)
        if (mv[i]) cidx[b * Kn + pos++] = t * 8 + i;
    if (t == 255) {
        int total = sums[255];
        if (total == 0) { cidx[b * Kn] = 0; total = 1; }
        cnt[b] = total;
    }
}

// ---------------------------------------------------------------------------
// prep_split: Wk -> x512 fp16 hi/lo split; Wo -> Wot (bf16 transpose).
// ---------------------------------------------------------------------------
__global__ __launch_bounds__(256) void prep_split(
    const float* __restrict__ Wk, const float* __restrict__ Wo,
    f16* __restrict__ Wk_h, f16* __restrict__ Wk_l, short* __restrict__ Wot)
{
    int e = blockIdx.x * 256 + threadIdx.x;
    float v = Wk[e] * 512.0f;
    f16 h = (f16)v;
    Wk_h[e] = h; Wk_l[e] = (f16)((v - (float)h) * 2048.0f);
    int r = e >> 9, c = e & 511;
    Wot[c * 512 + r] = bf16r(Wo[e]);
}

// ---------------------------------------------------------------------------
// prep_vec: wvec[h] = dot(Wk[h,:], bq)/512 (beta basis, scale-matched to qM);
// cvec[n] = bv.Wo + bo.
// ---------------------------------------------------------------------------
__global__ __launch_bounds__(512) void prep_vec(
    const float* __restrict__ Wk, const float* __restrict__ Wo,
    const float* __restrict__ bq, const float* __restrict__ bv,
    const float* __restrict__ bo,
    float* __restrict__ wvec, float* __restrict__ cvec)
{
    int t = threadIdx.x;
    float s = 0.f;
    for (int n = 0; n < 512; n += 4) {
        f32x4 a = *(const f32x4*)(Wk + (size_t)t * 512 + n);
        f32x4 q = *(const f32x4*)(bq + n);
        s += a[0]*q[0] + a[1]*q[1] + a[2]*q[2] + a[3]*q[3];
    }
    wvec[t] = s * (1.0f / 512.0f);
    float s2 = 0.f;
    for (int h = 0; h < 512; ++h) s2 += bv[h] * Wo[h * 512 + t];
    cvec[t] = s2 + bo[t];
}

// ---------------------------------------------------------------------------
// gemm_split<PREP>: fp16x2 3-product GEMM_BT, 64m x 128n tile, 48KB LDS dbuf.
//  PREP=0: qM = (A.Bt)/512, split out [m][n]
//  PREP=1: Mt = A.Bt (=M x512), split out TRANSPOSED [n][m]
// ---------------------------------------------------------------------------
template<int PREP>
__global__ __launch_bounds__(256) void gemm_split(
    const float* __restrict__ Af,
    const f16* __restrict__ Bh_g, const f16* __restrict__ Bl_g,
    f16* __restrict__ Oh, f16* __restrict__ Ol)
{
    __shared__ __align__(16) f16 Ah[2][2048], Al[2][2048], Bh[2][4096], Bl[2][4096];
    const int tid = threadIdx.x, lane = tid & 63, wid = tid >> 6;
    const int l15 = lane & 15, lg = lane >> 4;
    const int m0 = blockIdx.x * 64, n0 = blockIdx.y * 128;
    const int srow = lane >> 2, sg = lane & 3;
    const int ar0 = tid >> 3, ac0 = (tid & 7) * 4;

    auto stageB = [&](int buf, int ks) {
        const int k0 = ks << 5;
        #pragma unroll
        for (int h = 0; h < 2; ++h) {
            int s = wid + h * 4;
            int row = s * 16 + srow;
            int goff = k0 + ((sg ^ swz(row)) << 3);
            gl_lds16(Bh_g + (size_t)(n0 + row) * Hn + goff, &Bh[buf][s * 512]);
            gl_lds16(Bl_g + (size_t)(n0 + row) * Hn + goff, &Bl[buf][s * 512]);
        }
    };
    auto writeA = [&](int buf, const f32x4* av) {
        #pragma unroll
        for (int rr = 0; rr < 2; ++rr) {
            int row = ar0 + rr * 32;
            f16x4 oh, ol;
            #pragma unroll
            for (int j = 0; j < 4; ++j) {
                f16 hh = (f16)av[rr][j];
                oh[j] = hh;
                ol[j] = (f16)((av[rr][j] - (float)hh) * 2048.0f);
            }
            int off = row * 32 + (((ac0 >> 3) ^ swz(row)) << 3) + (ac0 & 7);
            *(f16x4*)&Ah[buf][off] = oh;
            *(f16x4*)&Al[buf][off] = ol;
        }
    };

    const float* aSrc[2];
    #pragma unroll
    for (int rr = 0; rr < 2; ++rr)
        aSrc[rr] = Af + (size_t)(m0 + ar0 + rr * 32) * Hn;

    f32x4 a0[4][2] = {}, a1[4][2] = {};
    {
        f32x4 av[2];
        #pragma unroll
        for (int rr = 0; rr < 2; ++rr) av[rr] = *(const f32x4*)(aSrc[rr] + ac0);
        stageB(0, 0);
        writeA(0, av);
    }
    __syncthreads();
    #pragma unroll 1
    for (int ks = 0; ks < 16; ++ks) {
        const int cur = ks & 1, nxt = cur ^ 1;
        f32x4 av[2];
        if (ks < 15) {
            const int k1 = (ks + 1) << 5;
            #pragma unroll
            for (int rr = 0; rr < 2; ++rr) av[rr] = *(const f32x4*)(aSrc[rr] + k1 + ac0);
            stageB(nxt, ks + 1);
        }
        f16x8 fbh[2], fbl[2];
        #pragma unroll
        for (int fj = 0; fj < 2; ++fj) {
            int row = wid * 32 + fj * 16 + l15;
            int off = row * 32 + ((lg ^ swz(row)) << 3);
            fbh[fj] = *(f16x8*)&Bh[cur][off];
            fbl[fj] = *(f16x8*)&Bl[cur][off];
        }
        #pragma unroll
        for (int fi = 0; fi < 4; ++fi) {
            int row = fi * 16 + l15;
            int off = row * 32 + ((lg ^ swz(row)) << 3);
            f16x8 fah = *(f16x8*)&Ah[cur][off];
            f16x8 fal = *(f16x8*)&Al[cur][off];
            #pragma unroll
            for (int fj = 0; fj < 2; ++fj) {
                a0[fi][fj] = MFMA16(fah, fbh[fj], a0[fi][fj]);
                a1[fi][fj] = MFMA16(fah, fbl[fj], a1[fi][fj]);
                a1[fi][fj] = MFMA16(fal, fbh[fj], a1[fi][fj]);
            }
        }
        if (ks < 15) writeA(nxt, av);
        __syncthreads();
    }
    #pragma unroll
    for (int fi = 0; fi < 4; ++fi)
    #pragma unroll
    for (int fj = 0; fj < 2; ++fj)
    #pragma unroll
    for (int j = 0; j < 4; ++j) {
        int m = m0 + fi * 16 + lg * 4 + j;
        int n = n0 + wid * 32 + fj * 16 + l15;
        float v = a0[fi][fj][j] + a1[fi][fj][j] * (1.0f / 2048.0f);
        if (PREP == 0) v *= (1.0f / 512.0f);
        f16 h = (f16)v;
        f16 lo = (f16)((v - (float)h) * 2048.0f);
        size_t o = PREP ? ((size_t)n * Hn + m) : ((size_t)m * Hn + n);
        Oh[o] = h; Ol[o] = lo;
    }
}

// ---------------------------------------------------------------------------
// gemm_bfk<MODE>: bf16 GEMM_BT, 64m x 128n tile, A f32->bf16 on the fly.
//  MODE=0: NtB prep — A=Wv direct rows, out bf16 TRANSPOSED [n][m], no bias.
//  MODE=1: res — A rows gathered from value via idxArr, out f32 + cvec.
// ---------------------------------------------------------------------------
template<int MODE>
__global__ __launch_bounds__(256) void gemm_bfk(
    const float* __restrict__ Af, const short* __restrict__ Bt,
    const float* __restrict__ cvec, const int* __restrict__ idxArr,
    void* __restrict__ Out)
{
    __shared__ __align__(16) short As[2][2048], Bs[2][4096];
    const int tid = threadIdx.x, lane = tid & 63, wid = tid >> 6;
    const int l15 = lane & 15, lg = lane >> 4;
    const int m0 = blockIdx.x * 64, n0 = blockIdx.y * 128;
    const int srow = lane >> 2, sg = lane & 3;
    const int ar0 = tid >> 3, ac0 = (tid & 7) * 4;

    const float* aSrc[2];
    #pragma unroll
    for (int rr = 0; rr < 2; ++rr) {
        int row = ar0 + rr * 32;
        size_t grow;
        if (MODE == 1) {
            int b = m0 >> 11;
            grow = (size_t)(b * Kn + idxArr[m0 + row]);
        } else {
            grow = (size_t)(m0 + row);
        }
        aSrc[rr] = Af + grow * Hn;
    }

    auto stageB = [&](int buf, int ks) {
        const int k0 = ks << 5;
        #pragma unroll
        for (int h = 0; h < 2; ++h) {
            int s = wid + h * 4;
            int row = s * 16 + srow;
            int goff = k0 + ((sg ^ swz(row)) << 3);
            gl_lds16(Bt + (size_t)(n0 + row) * Hn + goff, &Bs[buf][s * 512]);
        }
    };
    auto writeA = [&](int buf, const f32x4* av) {
        #pragma unroll
        for (int rr = 0; rr < 2; ++rr) {
            int row = ar0 + rr * 32;
            s16x4 o;
            #pragma unroll
            for (int j = 0; j < 4; ++j) o[j] = bf16r(av[rr][j]);
            int off = row * 32 + (((ac0 >> 3) ^ swz(row)) << 3) + (ac0 & 7);
            *(s16x4*)&As[buf][off] = o;
        }
    };

    f32x4 acc[4][2] = {};
    {
        f32x4 av[2];
        #pragma unroll
        for (int rr = 0; rr < 2; ++rr) av[rr] = *(const f32x4*)(aSrc[rr] + ac0);
        stageB(0, 0);
        writeA(0, av);
    }
    __syncthreads();
    #pragma unroll 1
    for (int ks = 0; ks < 16; ++ks) {
        const int cur = ks & 1, nxt = cur ^ 1;
        f32x4 av[2];
        if (ks < 15) {
            const int k1 = (ks + 1) << 5;
            #pragma unroll
            for (int rr = 0; rr < 2; ++rr) av[rr] = *(const f32x4*)(aSrc[rr] + k1 + ac0);
            stageB(nxt, ks + 1);
        }
        s16x8 fb[2];
        #pragma unroll
        for (int fj = 0; fj < 2; ++fj) {
            int row = wid * 32 + fj * 16 + l15;
            fb[fj] = *(s16x8*)&Bs[cur][row * 32 + ((lg ^ swz(row)) << 3)];
        }
        #pragma unroll
        for (int fi = 0; fi < 4; ++fi) {
            int row = fi * 16 + l15;
            s16x8 fa = *(s16x8*)&As[cur][row * 32 + ((lg ^ swz(row)) << 3)];
            #pragma unroll
            for (int fj = 0; fj < 2; ++fj)
                acc[fi][fj] = MFMAB16(fa, fb[fj], acc[fi][fj]);
        }
        if (ks < 15) writeA(nxt, av);
        __syncthreads();
    }
    #pragma unroll
    for (int fi = 0; fi < 4; ++fi)
    #pragma unroll
    for (int fj = 0; fj < 2; ++fj)
    #pragma unroll
    for (int j = 0; j < 4; ++j) {
        int m = m0 + fi * 16 + lg * 4 + j;
        int n = n0 + wid * 32 + fj * 16 + l15;
        if (MODE == 0) {
            ((short*)Out)[(size_t)n * Hn + m] = bf16r(acc[fi][fj][j]);
        } else {
            ((float*)Out)[(size_t)m * Hn + n] = acc[fi][fj][j] + cvec[n];
        }
    }
}

// ---------------------------------------------------------------------------
// kconv: gathered raw-k rows -> fp16 HI only (compacted layout) + beta.
// ---------------------------------------------------------------------------
__global__ __launch_bounds__(256) void kconv(
    const float* __restrict__ key_, const int* __restrict__ cidx,
    const int* __restrict__ cnt, const float* __restrict__ wvec,
    f16* __restrict__ Kc_h, float* __restrict__ beta)
{
    int wid = threadIdx.x >> 6, lane = threadIdx.x & 63;
    int b = blockIdx.y, j = blockIdx.x * 4 + wid;
    int cn = cnt[b];
    if (j >= cn) return;
    const float* src = key_ + (size_t)(b * Kn + cidx[b * Kn + j]) * Hn;
    size_t dst = (size_t)(b * Kn + j) * Hn;
    float s = 0.f;
    #pragma unroll
    for (int i = 0; i < 2; ++i) {
        int c0 = lane * 8 + i * 4;
        f32x4 v = *(const f32x4*)(src + c0);
        f32x4 w = *(const f32x4*)(wvec + c0);
        f16x4 oh;
        #pragma unroll
        for (int e = 0; e < 4; ++e) {
            oh[e] = (f16)v[e];
            s += v[e] * w[e];
        }
        *(f16x4*)(Kc_h + dst + c0) = oh;
    }
    #pragma unroll
    for (int sm = 1; sm < 64; sm <<= 1) s += __shfl_xor(s, sm, 64);
    if (lane == 0) beta[b * Kn + j] = s;
}

// ---------------------------------------------------------------------------
// energy_approx: hi*hi-only f16 GEMM, 128q x 128k tile, 2x2 waves, 32KB LDS.
// Writes approx energy row-major f16 [m][2048] (+beta, -inf for OOB cols).
// |approx - exact| <= ~0.4 worst case; refine uses window 1.0.
// ---------------------------------------------------------------------------
__global__ __launch_bounds__(256) void energy_approx(
    const f16* __restrict__ Qh, const f16* __restrict__ Kh,
    const float* __restrict__ beta, const int* __restrict__ cnt,
    f16* __restrict__ approxE)
{
    __shared__ __align__(16) f16 Ah[2][4096], Bh[2][4096];
    const int tid = threadIdx.x, lane = tid & 63, wid = tid >> 6;
    const int wr = wid >> 1, wc = wid & 1, l15 = lane & 15, lg = lane >> 4;
    const int qt = blockIdx.x, kc = blockIdx.y, b = blockIdx.z;
    const int cn = cnt[b];
    const int kbase = kc << 7;
    if (kbase >= cn) return;
    const int m0 = b * Qn + qt * 128;
    const int kr0 = b * Kn + kbase;
    const int srow = lane >> 2, sg = lane & 3;

    auto stage = [&](int buf, int ks) {
        const int k0 = ks << 5;
        #pragma unroll
        for (int h = 0; h < 2; ++h) {
            int s = wid + h * 4;
            int row = s * 16 + srow;
            int goff = k0 + ((sg ^ swz(row)) << 3);
            gl_lds16(Qh + (size_t)(m0 + row) * Hn + goff, &Ah[buf][s * 512]);
            gl_lds16(Kh + (size_t)(kr0 + row) * Hn + goff, &Bh[buf][s * 512]);
        }
    };

    f32x4 acc[4][4] = {};
    stage(0, 0);
    __syncthreads();
    #pragma unroll 1
    for (int ks = 0; ks < 16; ++ks) {
        const int cur = ks & 1;
        if (ks < 15) stage(cur ^ 1, ks + 1);
        f16x8 fb[4];
        #pragma unroll
        for (int fj = 0; fj < 4; ++fj) {
            int row = wc * 64 + fj * 16 + l15;
            fb[fj] = *(f16x8*)&Bh[cur][row * 32 + ((lg ^ swz(row)) << 3)];
        }
        #pragma unroll
        for (int fi = 0; fi < 4; ++fi) {
            int row = wr * 64 + fi * 16 + l15;
            f16x8 fa = *(f16x8*)&Ah[cur][row * 32 + ((lg ^ swz(row)) << 3)];
            #pragma unroll
            for (int fj = 0; fj < 4; ++fj)
                acc[fi][fj] = MFMA16(fa, fb[fj], acc[fi][fj]);
        }
        __syncthreads();
    }
    const f16 NEGI = (f16)(-__builtin_inff());
    float bet[4]; int valid[4];
    #pragma unroll
    for (int fj = 0; fj < 4; ++fj) {
        int lc = wc * 64 + fj * 16 + l15;
        valid[fj] = (kbase + lc < cn);
        bet[fj] = valid[fj] ? beta[b * Kn + kbase + lc] : 0.0f;
    }
    #pragma unroll
    for (int fi = 0; fi < 4; ++fi)
    #pragma unroll
    for (int fj = 0; fj < 4; ++fj)
    #pragma unroll
    for (int j = 0; j < 4; ++j) {
        int row = wr * 64 + fi * 16 + lg * 4 + j;
        int col = wc * 64 + fj * 16 + l15;
        f16 out = valid[fj] ? (f16)(acc[fi][fj][j] + bet[fj]) : NEGI;
        approxE[(size_t)(m0 + row) * Kn + kbase + col] = out;
    }
}

// ---------------------------------------------------------------------------
// refine: one wave per q-row. Scan approx row -> wave max -> candidates
// within 1.0 -> exact f32 dot (reconstructed qM x raw key) for rows with
// >1 candidate. np tie-break (lowest original index). Writes idxArr.
// ---------------------------------------------------------------------------
__global__ __launch_bounds__(256) void refine(
    const f16* __restrict__ approxE,
    const f16* __restrict__ qMh, const f16* __restrict__ qMl,
    const float* __restrict__ key_, const float* __restrict__ beta,
    const int* __restrict__ cidx, const int* __restrict__ cnt,
    int* __restrict__ idxArr)
{
    const int wid = threadIdx.x >> 6, lane = threadIdx.x & 63;
    const int m = blockIdx.x * 4 + wid;
    const int b = m >> 11;
    const int cn = cnt[b];
    const int nc128 = ((cn + 127) >> 7) << 7;
    const float NEGINF = -__builtin_inff();
    const f16* row = approxE + (size_t)m * Kn;

    f16x8 c[4];
    float fmaxv = NEGINF;
    #pragma unroll
    for (int g = 0; g < 4; ++g) {
        int cb = g * 512 + lane * 8;
        if (cb < nc128) {
            c[g] = *(const f16x8*)(row + cb);
            #pragma unroll
            for (int p = 0; p < 8; ++p) fmaxv = fmaxf(fmaxv, (float)c[g][p]);
        } else {
            #pragma unroll
            for (int p = 0; p < 8; ++p) c[g][p] = (f16)NEGINF;
        }
    }
    #pragma unroll
    for (int sm = 1; sm < 64; sm <<= 1) fmaxv = fmaxf(fmaxv, __shfl_xor(fmaxv, sm, 64));
    const float thr = fmaxv - 1.0f;

    float q8[8];
    int haveQ = 0;
    float bestV = NEGINF; int bestOrig = 0x7fffffff;
    int ncand = 0, firstJ = -1;

    #pragma unroll
    for (int g = 0; g < 4; ++g) {
        #pragma unroll
        for (int p = 0; p < 8; ++p) {
            unsigned long long mb = __ballot((float)c[g][p] >= thr);
            while (mb) {
                int L = __builtin_ctzll(mb);
                mb &= mb - 1;
                int j = g * 512 + L * 8 + p;
                ++ncand;
                if (ncand == 1) { firstJ = j; continue; }
                if (!haveQ) {
                    haveQ = 1;
                    int h0 = lane * 8;
                    f16x8 qh = *(const f16x8*)(qMh + (size_t)m * Hn + h0);
                    f16x8 ql = *(const f16x8*)(qMl + (size_t)m * Hn + h0);
                    #pragma unroll
                    for (int e = 0; e < 8; ++e)
                        q8[e] = (float)qh[e] + (float)ql[e] * (1.0f / 2048.0f);
                    // evaluate the deferred first candidate
                    int o1 = cidx[b * Kn + firstJ];
                    const float* kr = key_ + ((size_t)(b * Kn + o1)) * Hn + lane * 8;
                    float d = 0.f;
                    #pragma unroll
                    for (int e = 0; e < 8; ++e) d += q8[e] * kr[e];
                    #pragma unroll
                    for (int sm = 1; sm < 64; sm <<= 1) d += __shfl_xor(d, sm, 64);
                    d += beta[b * Kn + firstJ];
                    bestV = d; bestOrig = o1;
                }
                int orig = cidx[b * Kn + j];
                const float* kr = key_ + ((size_t)(b * Kn + orig)) * Hn + lane * 8;
                float d = 0.f;
                #pragma unroll
                for (int e = 0; e < 8; ++e) d += q8[e] * kr[e];
                #pragma unroll
                for (int sm = 1; sm < 64; sm <<= 1) d += __shfl_xor(d, sm, 64);
                d += beta[b * Kn + j];
                if (d > bestV || (d == bestV && orig < bestOrig)) { bestV = d; bestOrig = orig; }
            }
        }
    }
    if (ncand == 1) bestOrig = cidx[b * Kn + firstJ];
    if (lane == 0) idxArr[m] = bestOrig;
}

// ---------------------------------------------------------------------------
// score_fill: one-hot rows, writes the ENTIRE score region (erases scratch).
// ---------------------------------------------------------------------------
__global__ __launch_bounds__(256) void score_fill(
    const int* __restrict__ idxArr, float* __restrict__ score)
{
    int m = blockIdx.x;
    int c = idxArr[m];
    float* row = score + (size_t)m * Kn;
    int t = threadIdx.x;
    #pragma unroll
    for (int i = 0; i < 2; ++i) {
        int v = t + i * 256;
        f32x4 val = {0.f, 0.f, 0.f, 0.f};
        if ((c >> 2) == v) val[c & 3] = 1.0f;
        *(f32x4*)(row + v * 4) = val;
    }
}

// ---------------------------------------------------------------------------
extern "C" void kernel_launch(void* const* d_in, const int* in_sizes, int n_in,
                              void* d_out, int out_size, void* d_ws, size_t ws_size,
                              hipStream_t stream)
{
    const float* query = (const float*)d_in[0];
    const float* key_  = (const float*)d_in[1];
    const float* value = (const float*)d_in[2];
    const int*   mask  = (const int*)d_in[3];
    const float* Wq = (const float*)d_in[4];
    const float* bq = (const float*)d_in[5];
    const float* Wk = (const float*)d_in[6];
    const float* bv = (const float*)d_in[9];
    const float* Wv = (const float*)d_in[8];
    const float* Wo = (const float*)d_in[10];
    const float* bo = (const float*)d_in[11];

    float* res = (float*)d_out;                       // (B,Q,H) f32
    float* scoreBase = res + (size_t)Mn * Hn;         // (B,Q,K) f32, 134 MB
    char* sc = (char*)scoreBase;                      // scratch inside score region
    constexpr size_t MB = 1u << 20;
    f16*   qM_h = (f16*)(sc + 0 * MB);                // 16 MB
    f16*   qM_l = (f16*)(sc + 16 * MB);               // 16 MB
    f16*   Kc_h = (f16*)(sc + 32 * MB);               // 16 MB
    f16*   apxE = (f16*)(sc + 48 * MB);               // Mn*Kn*2 = 64 MB
    char*  wb   = sc + 112 * MB;
    f16*   Mt_h = (f16*)(wb);
    f16*   Mt_l = (f16*)(wb + 524288);
    f16*   Wk_h = (f16*)(wb + 2 * 524288);
    f16*   Wk_l = (f16*)(wb + 3 * 524288);
    short* Wot  = (short*)(wb + 4 * 524288);
    short* NtB  = (short*)(wb + 5 * 524288);
    float* wvec = (float*)(wb + 6 * 524288);
    float* cvec = (float*)(wb + 6 * 524288 + 4096);
    float* beta = (float*)(wb + 6 * 524288 + 8192);              // 64 KB
    int*   cidx = (int*)(wb + 6 * 524288 + 8192 + 65536);        // 64 KB

    int*   idxArr = (int*)d_ws;                       // Mn ints
    int*   cnt    = (int*)d_ws + Mn;                  // 8 ints

    compact_mask<<<Bn, 256, 0, stream>>>(mask, cidx, cnt);
    prep_split<<<1024, 256, 0, stream>>>(Wk, Wo, Wk_h, Wk_l, Wot);
    prep_vec<<<1, 512, 0, stream>>>(Wk, Wo, bq, bv, bo, wvec, cvec);

    // Mt = (Wq . Wk^T) x512, split, transposed  (tiny)
    gemm_split<1><<<dim3(8, 4), 256, 0, stream>>>(Wq, Wk_h, Wk_l, Mt_h, Mt_l);
    // NtB = (Wv . Wo)^T bf16  (tiny)
    gemm_bfk<0><<<dim3(8, 4), 256, 0, stream>>>(Wv, Wot, nullptr, nullptr, NtB);
    // qM = query . M  (the only big projection GEMM left)
    gemm_split<0><<<dim3(Mn / 64, 4), 256, 0, stream>>>(query, Mt_h, Mt_l, qM_h, qM_l);
    // raw-k hi-split + beta
    kconv<<<dim3(512, Bn), 256, 0, stream>>>(key_, cidx, cnt, wvec, Kc_h, beta);

    energy_approx<<<dim3(Qn / 128, 16, Bn), 256, 0, stream>>>(
        qM_h, Kc_h, beta, cnt, apxE);

    refine<<<Mn / 4, 256, 0, stream>>>(
        apxE, qM_h, qM_l, key_, beta, cidx, cnt, idxArr);

    // res = value[argmax] . N + c   (gathered A, one GEMM)
    gemm_bfk<1><<<dim3(Mn / 64, 4), 256, 0, stream>>>(value, NtB, cvec, idxArr, res);

    score_fill<<<Mn, 256, 0, stream>>>(idxArr, scoreBase);
}